// Round 2
// baseline (224.492 us; speedup 1.0000x reference)
//
#include <hip/hip_runtime.h>
#include <math.h>

// Problem constants
#define NSEQ 4096      // N
#define MFT  4096      // complex FFT length (even/odd pack of 2N=8192 real)
#define CHX  2048      // B*H*D channels of x
#define CHA  512       // H*D channels of a

// LDS padding: i + (i>>5) keeps every Stockham stage's reads/writes <=2-way
// bank aliasing (free on CDNA4 per m136). Max padded index 4095+127 = 4222.
#define LPAD 4224
static __device__ __forceinline__ int pad(int i) { return i + (i >> 5); }

// ---------------------------------------------------------------- wave reduce
static __device__ __forceinline__ float wsum64(float v) {
    v += __shfl_xor(v, 1);
    v += __shfl_xor(v, 2);
    v += __shfl_xor(v, 4);
    v += __shfl_xor(v, 8);
    v += __shfl_xor(v, 16);
    v += __shfl_xor(v, 32);
    return v;
}

// ---------------------------------------------------------------- twiddles
// tw[t] = e^{-2*pi*i*t/4096}
__global__ __launch_bounds__(256) void k_twiddle(float2* __restrict__ tw) {
    int t = blockIdx.x * 256 + threadIdx.x;
    float fr = (float)t * (2.0f / (float)MFT);
    tw[t] = make_float2(cospif(fr), -sinpif(fr));
}

// ---------------------------------------------------------------- transpose
// dst[c][r] = src[r][c], per slab of R*C. grid = (C/64, R/64, slabs), 256 thr.
__global__ __launch_bounds__(256) void k_transpose(const float* __restrict__ src,
                                                   float* __restrict__ dst,
                                                   int R, int C) {
    __shared__ float tile[64][65];
    size_t slab = (size_t)blockIdx.z * (size_t)R * (size_t)C;
    int c0 = blockIdx.x * 64, r0 = blockIdx.y * 64;
    int t = threadIdx.x;
    int tc = t & 63, t4 = t >> 6;
    const float* s = src + slab + (size_t)r0 * C + c0;
#pragma unroll
    for (int k = 0; k < 16; ++k) {
        int rr = t4 + k * 4;
        tile[rr][tc] = s[(size_t)rr * C + tc];
    }
    __syncthreads();
    float* d = dst + slab + (size_t)c0 * R + r0;
#pragma unroll
    for (int k = 0; k < 16; ++k) {
        int cc = t4 + k * 4;
        d[(size_t)cc * R + tc] = tile[tc][cc];
    }
}

// ---------------------------------------------------------------- RPE MLP
// aU[m][c], c = h*64+d, m = 0..4095: aU[m][c] = silu(gamma^m * rpe(m)[c]).
// (The reference's trailing zero-row a[4096] multiplies only x[n-4096], which
// is zero-padded for all kept outputs n<4096 -> drop it.)
static __device__ __forceinline__ void ln_pair(float& x0, float& x1, float w, float b) {
    float mu0 = wsum64(x0) * (1.0f / 64.0f);
    float mu1 = wsum64(x1) * (1.0f / 64.0f);
    float d0 = x0 - mu0, d1 = x1 - mu1;
    float v0 = wsum64(d0 * d0) * (1.0f / 64.0f);
    float v1 = wsum64(d1 * d1) * (1.0f / 64.0f);
    x0 = d0 * rsqrtf(v0 + 1e-5f) * w + b;
    x1 = d1 * rsqrtf(v1 + 1e-5f) * w + b;
}

__global__ __launch_bounds__(256) void k_rpe(
    const float* __restrict__ pp_w, const float* __restrict__ pp_b,
    const float* __restrict__ ln_w, const float* __restrict__ ln_b,
    const float* __restrict__ lw,   const float* __restrict__ lb,
    const float* __restrict__ oln_w,const float* __restrict__ oln_b,
    const float* __restrict__ out_w,const float* __restrict__ out_b,
    float* __restrict__ aU)
{
    const int wave = threadIdx.x >> 6;
    const int lane = threadIdx.x & 63;
    const int mbase = (blockIdx.x * 4 + wave) * 2;
    const float m0 = (float)mbase, m1 = (float)(mbase + 1);

    float x0 = fmaf(m0, pp_w[lane], pp_b[lane]);
    float x1 = fmaf(m1, pp_w[lane], pp_b[lane]);

    for (int L = 0; L < 3; ++L) {
        ln_pair(x0, x1, ln_w[L * 64 + lane], ln_b[L * 64 + lane]);
        float r0 = fmaxf(x0, 0.0f), r1 = fmaxf(x1, 0.0f);
        float y0 = lb[L * 64 + lane], y1 = y0;
        const float* W = lw + L * 4096;
#pragma unroll 8
        for (int i = 0; i < 64; ++i) {
            float wi = W[i * 64 + lane];
            float a0 = __shfl(r0, i);
            float a1 = __shfl(r1, i);
            y0 = fmaf(a0, wi, y0);
            y1 = fmaf(a1, wi, y1);
        }
        x0 = y0; x1 = y1;
    }
    ln_pair(x0, x1, oln_w[lane], oln_b[lane]);
    float r0 = fmaxf(x0, 0.0f), r1 = fmaxf(x1, 0.0f);

    float acc0[8], acc1[8];
#pragma unroll
    for (int k = 0; k < 8; ++k) {
        float ob = out_b[k * 64 + lane];
        acc0[k] = ob; acc1[k] = ob;
    }
#pragma unroll 4
    for (int i = 0; i < 64; ++i) {
        float a0 = __shfl(r0, i);
        float a1 = __shfl(r1, i);
        const float* Wr = out_w + i * 512;
#pragma unroll
        for (int k = 0; k < 8; ++k) {
            float wv = Wr[k * 64 + lane];
            acc0[k] = fmaf(a0, wv, acc0[k]);
            acc1[k] = fmaf(a1, wv, acc1[k]);
        }
    }
    const float LOGG = -0.0010005003335835335f; // ln(0.999)
    float d0 = __expf(m0 * LOGG);               // m0==0 -> 1.0
    float d1 = __expf(m1 * LOGG);
    float* row0 = aU + (size_t)mbase * 512;
    float* row1 = row0 + 512;
#pragma unroll
    for (int k = 0; k < 8; ++k) {
        int c = k * 64 + lane;
        float v0 = acc0[k] * d0; v0 = v0 / (1.0f + __expf(-v0));
        float v1 = acc1[k] * d1; v1 = v1 / (1.0f + __expf(-v1));
        row0[c] = v0;
        row1[c] = v1;
    }
}

// ---------------------------------------------------------------- FFT core
// Stockham radix-4, 4096 pts, natural in -> natural out, ping-pong LDS.
// All LDS indices padded. Result ends in (r0,i0) after 6 stages.
template<bool INV>
static __device__ __forceinline__ void fft4096(float* r0, float* i0, float* r1, float* i1,
                                               const float2* __restrict__ tw) {
    float* sr = r0; float* si = i0; float* dr = r1; float* di = i1;
    int Ns = 1;
#pragma unroll
    for (int s = 0; s < 6; ++s) {
        __syncthreads();
        const int shift = 10 - 2 * s;   // 1024/Ns
#pragma unroll
        for (int jj = 0; jj < 4; ++jj) {
            const int j = threadIdx.x + (jj << 8);          // 0..1023
            float v0r = sr[pad(j)],        v0i = si[pad(j)];
            float v1r = sr[pad(j + 1024)], v1i = si[pad(j + 1024)];
            float v2r = sr[pad(j + 2048)], v2i = si[pad(j + 2048)];
            float v3r = sr[pad(j + 3072)], v3i = si[pad(j + 3072)];
            const int jm = j & (Ns - 1);
            const int t1 = jm << shift;
            float2 w1 = tw[t1];
            float2 w2 = tw[(t1 << 1) & (MFT - 1)];
            float2 w3 = tw[(t1 * 3) & (MFT - 1)];
            if (INV) { w1.y = -w1.y; w2.y = -w2.y; w3.y = -w3.y; }
            float t;
            t = v1r * w1.x - v1i * w1.y; v1i = v1r * w1.y + v1i * w1.x; v1r = t;
            t = v2r * w2.x - v2i * w2.y; v2i = v2r * w2.y + v2i * w2.x; v2r = t;
            t = v3r * w3.x - v3i * w3.y; v3i = v3r * w3.y + v3i * w3.x; v3r = t;
            const float a0r = v0r + v2r, a0i = v0i + v2i;
            const float a1r = v0r - v2r, a1i = v0i - v2i;
            const float a2r = v1r + v3r, a2i = v1i + v3i;
            const float a3r = v1r - v3r, a3i = v1i - v3i;
            const float b3r = INV ? -a3i : a3i;
            const float b3i = INV ?  a3r : -a3r;
            const int idxD = ((j & ~(Ns - 1)) << 2) | jm;
            dr[pad(idxD)]          = a0r + a2r; di[pad(idxD)]          = a0i + a2i;
            dr[pad(idxD + Ns)]     = a1r + b3r; di[pad(idxD + Ns)]     = a1i + b3i;
            dr[pad(idxD + 2 * Ns)] = a0r - a2r; di[pad(idxD + 2 * Ns)] = a0i - a2i;
            dr[pad(idxD + 3 * Ns)] = a1r - b3r; di[pad(idxD + 3 * Ns)] = a1i - b3i;
        }
        Ns <<= 2;
        float* tp;
        tp = sr; sr = dr; dr = tp;
        tp = si; si = di; di = tp;
    }
    __syncthreads();
}

// ---------------------------------------------------------------- forward FFT (a-side)
// One WG per channel row: 4096 reals read as 2048 float2 (even/odd pack),
// upper half zero (2N zero-padding). Writes packed spectrum.
__global__ __launch_bounds__(256) void k_fft_fwd(const float2* __restrict__ src,
                                                 float2* __restrict__ dst,
                                                 const float2* __restrict__ tw) {
    __shared__ float sRe[2][LPAD];
    __shared__ float sIm[2][LPAD];
    const float2* s = src + (size_t)blockIdx.x * 2048;
    for (int i = threadIdx.x; i < 2048; i += 256) {
        float2 v = s[i];
        sRe[0][pad(i)] = v.x;          sIm[0][pad(i)] = v.y;
        sRe[0][pad(i + 2048)] = 0.0f;  sIm[0][pad(i + 2048)] = 0.0f;
    }
    fft4096<false>(sRe[0], sIm[0], sRe[1], sIm[1], tw);
    float2* d = dst + (size_t)blockIdx.x * 4096;
    for (int i = threadIdx.x; i < 4096; i += 256) {
        d[i] = make_float2(sRe[0][pad(i)], sIm[0][pad(i)]);
    }
}

// ---------------------------------------------------------------- fused FFT(x) + conv + iFFT
// Per x-channel bc = b*512 + h*64 + d:
//   fwd FFT of packed x-row (LDS-resident), unpack both packed spectra to the
//   true length-8192 rfft bins, multiply, repack into W = spectrum of
//   (y_even + i*y_odd), inverse FFT, store first 4096 reals.
// Eliminates the Zx global round-trip entirely (-134 MB HBM).
__global__ __launch_bounds__(256) void k_fft_conv_inv(const float2* __restrict__ xrow,
                                                      const float2* __restrict__ Za,
                                                      const float2* __restrict__ tw,
                                                      float* __restrict__ yT) {
    __shared__ float sRe[2][LPAD];
    __shared__ float sIm[2][LPAD];
    const int bc = blockIdx.x;          // 0..2047
    const int ca = bc & 511;            // h*64 + d
    const float2* s = xrow + (size_t)bc * 2048;
    for (int i = threadIdx.x; i < 2048; i += 256) {
        float2 v = s[i];
        sRe[0][pad(i)] = v.x;          sIm[0][pad(i)] = v.y;
        sRe[0][pad(i + 2048)] = 0.0f;  sIm[0][pad(i + 2048)] = 0.0f;
    }
    fft4096<false>(sRe[0], sIm[0], sRe[1], sIm[1], tw);  // X packed in buf0

    const float2* za = Za + (size_t)ca * 4096;
    // no barrier needed here: fft4096 ends with __syncthreads()
    for (int f = threadIdx.x; f <= 2048; f += 256) {
        const int fm = (4096 - f) & 4095;
        float2 Xf = make_float2(sRe[0][pad(f)],  sIm[0][pad(f)]);
        float2 Xm = make_float2(sRe[0][pad(fm)], sIm[0][pad(fm)]);
        float2 Af = za[f], Am = za[fm];
        // even/odd sub-spectra: E = (Z[f]+conj(Z[-f]))/2, O = -i(Z[f]-conj(Z[-f]))/2
        float Exr = 0.5f * (Xf.x + Xm.x), Exi = 0.5f * (Xf.y - Xm.y);
        float Oxr = 0.5f * (Xf.y + Xm.y), Oxi = 0.5f * (Xm.x - Xf.x);
        float Ear = 0.5f * (Af.x + Am.x), Eai = 0.5f * (Af.y - Am.y);
        float Oar = 0.5f * (Af.y + Am.y), Oai = 0.5f * (Am.x - Af.x);
        // t = e^{-i*pi*f/4096}
        float fr = (float)f * (1.0f / 4096.0f);
        float cp = cospif(fr), sp = sinpif(fr);
        float tOxr = cp * Oxr + sp * Oxi, tOxi = cp * Oxi - sp * Oxr;
        float tOar = cp * Oar + sp * Oai, tOai = cp * Oai - sp * Oar;
        // X[f] = E + tO ; X[f+4096] = E - tO  (same for A)
        float Xpr = Exr + tOxr, Xpi = Exi + tOxi;
        float Xqr = Exr - tOxr, Xqi = Exi - tOxi;
        float Apr = Ear + tOar, Api = Eai + tOai;
        float Aqr = Ear - tOar, Aqi = Eai - tOai;
        // P = Y[f], Q = Y[f+4096]
        float Pr = Xpr * Apr - Xpi * Api, Pi = Xpr * Api + Xpi * Apr;
        float Qr = Xqr * Aqr - Xqi * Aqi, Qi = Xqr * Aqi + Xqi * Aqr;
        // Ye = (P+Q)/2 ; Yo = conj(t)*(P-Q)/2 ; W = Ye + i*Yo
        float Sr = 0.5f * (Pr + Qr), Si = 0.5f * (Pi + Qi);
        float Dr = 0.5f * (Pr - Qr), Di = 0.5f * (Pi - Qi);
        float Cr = cp * Dr - sp * Di, Ci = cp * Di + sp * Dr;
        sRe[1][pad(f)]  = Sr - Ci;  sIm[1][pad(f)]  = Si + Cr;
        sRe[1][pad(fm)] = Sr + Ci;  sIm[1][pad(fm)] = Cr - Si;  // W[-f] = conj(Ye - i*Yo)
    }
    fft4096<true>(sRe[1], sIm[1], sRe[0], sIm[0], tw);   // result in buf1
    const float sc = 1.0f / 4096.0f;
    float2* dst = (float2*)yT + (size_t)bc * 2048;
    for (int k = threadIdx.x; k < 2048; k += 256) {
        dst[k] = make_float2(sRe[1][pad(k)] * sc, sIm[1][pad(k)] * sc);
    }
}

// ---------------------------------------------------------------- launch
extern "C" void kernel_launch(void* const* d_in, const int* in_sizes, int n_in,
                              void* d_out, int out_size, void* d_ws, size_t ws_size,
                              hipStream_t stream) {
    const float* x     = (const float*)d_in[0];
    const float* pp_w  = (const float*)d_in[1];
    const float* pp_b  = (const float*)d_in[2];
    const float* ln_w  = (const float*)d_in[3];
    const float* ln_b  = (const float*)d_in[4];
    const float* lw    = (const float*)d_in[5];
    const float* lb    = (const float*)d_in[6];
    const float* oln_w = (const float*)d_in[7];
    const float* oln_b = (const float*)d_in[8];
    const float* out_w = (const float*)d_in[9];
    const float* out_b = (const float*)d_in[10];
    float* out = (float*)d_out;
    char* ws = (char*)d_ws;

    // ws layout (bytes), total ~67.2 MB:
    //   tw  @ 0       : 4096 float2                (32 KB)
    //   xT  @ 64K     : 2048x4096 f32  (33.55 MB)  x channel-major; aliased by yT
    //   aU  @ +33.5M  : 4096x512  f32  ( 8.39 MB)  rpe out, m-major
    //   aT  @ +8.39M  : 512x4096  f32  ( 8.39 MB)  rpe out, channel-major
    //   Za  @ +8.39M  : 512x4096  cplx (16.78 MB)  packed spectra of a
    float2* tw = (float2*)(ws);
    float*  xT = (float*)(ws + 65536u);
    float*  aU = (float*)(ws + 65536u + 33554432u);
    float*  aT = (float*)(ws + 65536u + 33554432u + 8388608u);
    float2* Za = (float2*)(ws + 65536u + 33554432u + 16777216u);
    float*  yT = xT;   // xT dead after the fused kernel consumes it

    k_twiddle<<<16, 256, 0, stream>>>(tw);
    // x [32 slabs][4096 n][64 d] -> xT [32][64 d][4096 n]
    k_transpose<<<dim3(1, 64, 32), 256, 0, stream>>>(x, xT, 4096, 64);
    k_rpe<<<512, 256, 0, stream>>>(pp_w, pp_b, ln_w, ln_b, lw, lb,
                                   oln_w, oln_b, out_w, out_b, aU);
    // aU [4096 m][512 c] -> aT [512 c][4096 m]
    k_transpose<<<dim3(8, 64, 1), 256, 0, stream>>>(aU, aT, 4096, 512);
    k_fft_fwd<<<CHA, 256, 0, stream>>>((const float2*)aT, Za, tw);
    k_fft_conv_inv<<<CHX, 256, 0, stream>>>((const float2*)xT, Za, tw, yT);
    // yT [32][64 d][4096 n] -> out [32][4096 n][64 d]
    k_transpose<<<dim3(64, 1, 32), 256, 0, stream>>>(yT, out, 64, 4096);
}

// Round 3
// 181.393 us; speedup vs baseline: 1.2376x; 1.2376x over previous
//
#include <hip/hip_runtime.h>
#include <math.h>

// Problem constants
#define NSEQ 4096      // N
#define MFT  4096      // complex FFT length (even/odd pack of 2N=8192 real)
#define CHX  2048      // B*H*D channels of x
#define CHA  512       // H*D channels of a

// LDS padding: i + (i>>5); max padded index 4095+127=4222 -> size 4224.
// Keeps every exchange read/write phase <=2-way bank aliasing (free, m136).
#define LPAD 4224
static __device__ __forceinline__ int pad(int i) { return i + (i >> 5); }

// ---------------------------------------------------------------- wave reduce
static __device__ __forceinline__ float wsum64(float v) {
    v += __shfl_xor(v, 1);
    v += __shfl_xor(v, 2);
    v += __shfl_xor(v, 4);
    v += __shfl_xor(v, 8);
    v += __shfl_xor(v, 16);
    v += __shfl_xor(v, 32);
    return v;
}

// ---------------------------------------------------------------- twiddles
// tw[t] = e^{-2*pi*i*t/4096}
__global__ __launch_bounds__(256) void k_twiddle(float2* __restrict__ tw) {
    int t = blockIdx.x * 256 + threadIdx.x;
    float fr = (float)t * (2.0f / (float)MFT);
    tw[t] = make_float2(cospif(fr), -sinpif(fr));
}

// ---------------------------------------------------------------- transpose
// dst[c][r] = src[r][c], per slab of R*C. grid = (C/64, R/64, slabs), 256 thr.
__global__ __launch_bounds__(256) void k_transpose(const float* __restrict__ src,
                                                   float* __restrict__ dst,
                                                   int R, int C) {
    __shared__ float tile[64][65];
    size_t slab = (size_t)blockIdx.z * (size_t)R * (size_t)C;
    int c0 = blockIdx.x * 64, r0 = blockIdx.y * 64;
    int t = threadIdx.x;
    int tc = t & 63, t4 = t >> 6;
    const float* s = src + slab + (size_t)r0 * C + c0;
#pragma unroll
    for (int k = 0; k < 16; ++k) {
        int rr = t4 + k * 4;
        tile[rr][tc] = s[(size_t)rr * C + tc];
    }
    __syncthreads();
    float* d = dst + slab + (size_t)c0 * R + r0;
#pragma unroll
    for (int k = 0; k < 16; ++k) {
        int cc = t4 + k * 4;
        d[(size_t)cc * R + tc] = tile[tc][cc];
    }
}

// ---------------------------------------------------------------- RPE MLP
// aU[m][c], c = h*64+d, m = 0..4095: aU[m][c] = silu(gamma^m * rpe(m)[c]).
static __device__ __forceinline__ void ln_pair(float& x0, float& x1, float w, float b) {
    float mu0 = wsum64(x0) * (1.0f / 64.0f);
    float mu1 = wsum64(x1) * (1.0f / 64.0f);
    float d0 = x0 - mu0, d1 = x1 - mu1;
    float v0 = wsum64(d0 * d0) * (1.0f / 64.0f);
    float v1 = wsum64(d1 * d1) * (1.0f / 64.0f);
    x0 = d0 * rsqrtf(v0 + 1e-5f) * w + b;
    x1 = d1 * rsqrtf(v1 + 1e-5f) * w + b;
}

__global__ __launch_bounds__(256) void k_rpe(
    const float* __restrict__ pp_w, const float* __restrict__ pp_b,
    const float* __restrict__ ln_w, const float* __restrict__ ln_b,
    const float* __restrict__ lw,   const float* __restrict__ lb,
    const float* __restrict__ oln_w,const float* __restrict__ oln_b,
    const float* __restrict__ out_w,const float* __restrict__ out_b,
    float* __restrict__ aU)
{
    const int wave = threadIdx.x >> 6;
    const int lane = threadIdx.x & 63;
    const int mbase = (blockIdx.x * 4 + wave) * 2;
    const float m0 = (float)mbase, m1 = (float)(mbase + 1);

    float x0 = fmaf(m0, pp_w[lane], pp_b[lane]);
    float x1 = fmaf(m1, pp_w[lane], pp_b[lane]);

    for (int L = 0; L < 3; ++L) {
        ln_pair(x0, x1, ln_w[L * 64 + lane], ln_b[L * 64 + lane]);
        float r0 = fmaxf(x0, 0.0f), r1 = fmaxf(x1, 0.0f);
        float y0 = lb[L * 64 + lane], y1 = y0;
        const float* W = lw + L * 4096;
#pragma unroll 8
        for (int i = 0; i < 64; ++i) {
            float wi = W[i * 64 + lane];
            float a0 = __shfl(r0, i);
            float a1 = __shfl(r1, i);
            y0 = fmaf(a0, wi, y0);
            y1 = fmaf(a1, wi, y1);
        }
        x0 = y0; x1 = y1;
    }
    ln_pair(x0, x1, oln_w[lane], oln_b[lane]);
    float r0 = fmaxf(x0, 0.0f), r1 = fmaxf(x1, 0.0f);

    float acc0[8], acc1[8];
#pragma unroll
    for (int k = 0; k < 8; ++k) {
        float ob = out_b[k * 64 + lane];
        acc0[k] = ob; acc1[k] = ob;
    }
#pragma unroll 4
    for (int i = 0; i < 64; ++i) {
        float a0 = __shfl(r0, i);
        float a1 = __shfl(r1, i);
        const float* Wr = out_w + i * 512;
#pragma unroll
        for (int k = 0; k < 8; ++k) {
            float wv = Wr[k * 64 + lane];
            acc0[k] = fmaf(a0, wv, acc0[k]);
            acc1[k] = fmaf(a1, wv, acc1[k]);
        }
    }
    const float LOGG = -0.0010005003335835335f; // ln(0.999)
    float d0 = __expf(m0 * LOGG);               // m0==0 -> 1.0
    float d1 = __expf(m1 * LOGG);
    float* row0 = aU + (size_t)mbase * 512;
    float* row1 = row0 + 512;
#pragma unroll
    for (int k = 0; k < 8; ++k) {
        int c = k * 64 + lane;
        float v0 = acc0[k] * d0; v0 = v0 / (1.0f + __expf(-v0));
        float v1 = acc1[k] * d1; v1 = v1 / (1.0f + __expf(-v1));
        row0[c] = v0;
        row1[c] = v1;
    }
}

// ---------------------------------------------------------------- register FFT
// 4096 = 16^3, 256 threads x 16 cplx in VGPRs, 3 radix-16 stages, 2 LDS
// exchanges (2r+2w per point vs 6r+6w for the old LDS Stockham).
static __device__ __forceinline__ void cmulrw(float& r, float& i, float wr, float wi) {
    float t = r * wr - i * wi;
    i = r * wi + i * wr;
    r = t;
}

template<bool INV>
static __device__ __forceinline__ void dft4(float& ar, float& ai, float& br, float& bi,
                                            float& cr, float& ci, float& dr, float& di) {
    float t0r = ar + cr, t0i = ai + ci, t1r = ar - cr, t1i = ai - ci;
    float t2r = br + dr, t2i = bi + di, t3r = br - dr, t3i = bi - di;
    float u3r = INV ? -t3i : t3i;
    float u3i = INV ?  t3r : -t3r;
    ar = t0r + t2r; ai = t0i + t2i;
    br = t1r + u3r; bi = t1i + u3i;
    cr = t0r - t2r; ci = t0i - t2i;
    dr = t1r - u3r; di = t1i - u3i;
}

// In-place DFT-16 (natural in, natural out), compile-time twiddles.
template<bool INV>
static __device__ __forceinline__ void radix16(float (&vr)[16], float (&vi)[16]) {
    const float C1 = 0.92387953251128674f;  // cos(pi/8)
    const float S1 = 0.38268343236508978f;  // sin(pi/8)
    const float R2 = 0.70710678118654752f;
    const float SG = INV ? 1.0f : -1.0f;
    // step 1: DFT4 over n_b groups {na, na+4, na+8, na+12}; slot na+4kb = A[na][kb]
#pragma unroll
    for (int na = 0; na < 4; ++na)
        dft4<INV>(vr[na], vi[na], vr[na + 4], vi[na + 4],
                  vr[na + 8], vi[na + 8], vr[na + 12], vi[na + 12]);
    // step 2: A[na][kb] *= W16^(na*kb)
    cmulrw(vr[5],  vi[5],   C1, SG * S1);   // m=1
    cmulrw(vr[9],  vi[9],   R2, SG * R2);   // m=2
    cmulrw(vr[13], vi[13],  S1, SG * C1);   // m=3
    cmulrw(vr[6],  vi[6],   R2, SG * R2);   // m=2
    {   // m=4: fwd *(0,-1); inv *(0,+1)
        float tmp = vr[10];
        if (INV) { vr[10] = -vi[10]; vi[10] =  tmp; }
        else     { vr[10] =  vi[10]; vi[10] = -tmp; }
    }
    cmulrw(vr[14], vi[14], -R2, SG * R2);   // m=6
    cmulrw(vr[7],  vi[7],   S1, SG * C1);   // m=3
    cmulrw(vr[11], vi[11], -R2, SG * R2);   // m=6
    cmulrw(vr[15], vi[15], -C1, -SG * S1);  // m=9
    // step 3: DFT4 over na groups [4kb + na] -> Y[kb + 4ka]
    float yr[16], yi[16];
#pragma unroll
    for (int kb = 0; kb < 4; ++kb) {
        float ar = vr[4*kb+0], ai = vi[4*kb+0], br = vr[4*kb+1], bi = vi[4*kb+1];
        float cr = vr[4*kb+2], ci = vi[4*kb+2], dr = vr[4*kb+3], di = vi[4*kb+3];
        dft4<INV>(ar, ai, br, bi, cr, ci, dr, di);
        yr[kb]      = ar; yi[kb]      = ai;
        yr[kb + 4]  = br; yi[kb + 4]  = bi;
        yr[kb + 8]  = cr; yi[kb + 8]  = ci;
        yr[kb + 12] = dr; yi[kb + 12] = di;
    }
#pragma unroll
    for (int k = 0; k < 16; ++k) { vr[k] = yr[k]; vi[k] = yi[k]; }
}

// Full 4096-pt FFT. Input: thread t holds x[t + 256*n3] in vr/vi[n3].
// Output: thread t holds X[t + 256*k1] in vr/vi[k1].
// Uses lRe/lIm (LPAD each) for the two exchanges; starts with a sync so any
// prior readers of the buffer are safe; ends with registers live (no sync).
template<bool INV>
static __device__ __forceinline__ void fft4096_reg(float (&vr)[16], float (&vi)[16],
    float* __restrict__ lRe, float* __restrict__ lIm,
    const float2* __restrict__ tw, int t)
{
    radix16<INV>(vr, vi);                       // over n3 -> k3
    __syncthreads();
#pragma unroll
    for (int k3 = 0; k3 < 16; ++k3) {
        int L = t + (k3 << 8);
        lRe[pad(L)] = vr[k3]; lIm[pad(L)] = vi[k3];
    }
    __syncthreads();
    {   // thread t = n1 + 16*k3 ; read over n2, twiddle W256^(n2*k3)
        int n1 = t & 15, k3 = t >> 4;
        float2 w = tw[k3 << 4];
        float wim = INV ? -w.y : w.y;
        float cr = 1.0f, ci = 0.0f;
#pragma unroll
        for (int n2 = 0; n2 < 16; ++n2) {
            int L = n1 + (n2 << 4) + (k3 << 8);
            float xr = lRe[pad(L)], xi = lIm[pad(L)];
            vr[n2] = xr * cr - xi * ci;
            vi[n2] = xr * ci + xi * cr;
            float ncr = cr * w.x - ci * wim;
            ci = cr * wim + ci * w.x; cr = ncr;
        }
    }
    radix16<INV>(vr, vi);                       // over n2 -> k2
    __syncthreads();
#pragma unroll
    for (int k2 = 0; k2 < 16; ++k2) {
        int L = t + (k2 << 8);
        lRe[pad(L)] = vr[k2]; lIm[pad(L)] = vi[k2];
    }
    __syncthreads();
    {   // thread t = k3 + 16*k2 ; read over n1 (16 consecutive), twiddle W4096^(n1*t)
        float2 w = tw[t];
        float wim = INV ? -w.y : w.y;
        float cr = 1.0f, ci = 0.0f;
#pragma unroll
        for (int n1 = 0; n1 < 16; ++n1) {
            int L = (t << 4) + n1;
            float xr = lRe[pad(L)], xi = lIm[pad(L)];
            vr[n1] = xr * cr - xi * ci;
            vi[n1] = xr * ci + xi * cr;
            float ncr = cr * w.x - ci * wim;
            ci = cr * wim + ci * w.x; cr = ncr;
        }
    }
    radix16<INV>(vr, vi);                       // over n1 -> k1
}

// ---------------------------------------------------------------- forward FFT (a-side)
__global__ __launch_bounds__(256, 4) void k_fft_fwd(const float2* __restrict__ src,
                                                    float2* __restrict__ dst,
                                                    const float2* __restrict__ tw) {
    __shared__ float lRe[LPAD];
    __shared__ float lIm[LPAD];
    const int t = threadIdx.x;
    const float2* s = src + (size_t)blockIdx.x * 2048;
    float vr[16], vi[16];
#pragma unroll
    for (int n3 = 0; n3 < 8; ++n3) {
        float2 v = s[t + (n3 << 8)];
        vr[n3] = v.x; vi[n3] = v.y;
    }
#pragma unroll
    for (int n3 = 8; n3 < 16; ++n3) { vr[n3] = 0.0f; vi[n3] = 0.0f; }
    fft4096_reg<false>(vr, vi, lRe, lIm, tw, t);
    float2* d = dst + (size_t)blockIdx.x * 4096;
#pragma unroll
    for (int k1 = 0; k1 < 16; ++k1) {
        d[t + (k1 << 8)] = make_float2(vr[k1], vi[k1]);
    }
}

// ---------------------------------------------------------------- fused FFT(x)+conv+iFFT
__global__ __launch_bounds__(256, 4) void k_fft_conv_inv(const float2* __restrict__ xrow,
                                                         const float2* __restrict__ Za,
                                                         const float2* __restrict__ tw,
                                                         float* __restrict__ yT) {
    __shared__ float lRe[LPAD];
    __shared__ float lIm[LPAD];
    const int t = threadIdx.x;
    const int bc = blockIdx.x;          // 0..2047
    const int ca = bc & 511;            // h*64 + d
    const float2* s = xrow + (size_t)bc * 2048;
    float vr[16], vi[16];
#pragma unroll
    for (int n3 = 0; n3 < 8; ++n3) {
        float2 v = s[t + (n3 << 8)];
        vr[n3] = v.x; vi[n3] = v.y;
    }
#pragma unroll
    for (int n3 = 8; n3 < 16; ++n3) { vr[n3] = 0.0f; vi[n3] = 0.0f; }
    fft4096_reg<false>(vr, vi, lRe, lIm, tw, t);   // X[t + 256*k1] in regs

    __syncthreads();                                // last exchange readers done
#pragma unroll
    for (int k1 = 0; k1 < 16; ++k1) {               // stage spectrum to LDS
        int L = t + (k1 << 8);
        lRe[pad(L)] = vr[k1]; lIm[pad(L)] = vi[k1];
    }
    __syncthreads();

    const float2* za = Za + (size_t)ca * 4096;
    for (int f = t; f <= 2048; f += 256) {
        const int fm = (4096 - f) & 4095;
        float Xfr = lRe[pad(f)],  Xfi = lIm[pad(f)];
        float Xmr = lRe[pad(fm)], Xmi = lIm[pad(fm)];
        float2 Af = za[f], Am = za[fm];
        // even/odd sub-spectra: E = (Z[f]+conj(Z[-f]))/2, O = -i(Z[f]-conj(Z[-f]))/2
        float Exr = 0.5f * (Xfr + Xmr), Exi = 0.5f * (Xfi - Xmi);
        float Oxr = 0.5f * (Xfi + Xmi), Oxi = 0.5f * (Xmr - Xfr);
        float Ear = 0.5f * (Af.x + Am.x), Eai = 0.5f * (Af.y - Am.y);
        float Oar = 0.5f * (Af.y + Am.y), Oai = 0.5f * (Am.x - Af.x);
        // t = e^{-i*pi*f/4096}
        float fr = (float)f * (1.0f / 4096.0f);
        float cp = cospif(fr), sp = sinpif(fr);
        float tOxr = cp * Oxr + sp * Oxi, tOxi = cp * Oxi - sp * Oxr;
        float tOar = cp * Oar + sp * Oai, tOai = cp * Oai - sp * Oar;
        float Xpr = Exr + tOxr, Xpi = Exi + tOxi;
        float Xqr = Exr - tOxr, Xqi = Exi - tOxi;
        float Apr = Ear + tOar, Api = Eai + tOai;
        float Aqr = Ear - tOar, Aqi = Eai - tOai;
        float Pr = Xpr * Apr - Xpi * Api, Pi = Xpr * Api + Xpi * Apr;
        float Qr = Xqr * Aqr - Xqi * Aqi, Qi = Xqr * Aqi + Xqi * Aqr;
        float Sr = 0.5f * (Pr + Qr), Si = 0.5f * (Pi + Qi);
        float Dr = 0.5f * (Pr - Qr), Di = 0.5f * (Pi - Qi);
        float Cr = cp * Dr - sp * Di, Ci = cp * Di + sp * Dr;
        lRe[pad(f)]  = Sr - Ci;  lIm[pad(f)]  = Si + Cr;
        lRe[pad(fm)] = Sr + Ci;  lIm[pad(fm)] = Cr - Si;   // W[-f] = conj(Ye - i*Yo)
    }
    __syncthreads();
#pragma unroll
    for (int n3 = 0; n3 < 16; ++n3) {               // load W for inverse FFT
        int L = t + (n3 << 8);
        vr[n3] = lRe[pad(L)]; vi[n3] = lIm[pad(L)];
    }
    fft4096_reg<true>(vr, vi, lRe, lIm, tw, t);     // y_packed[t + 256*k1] in regs

    const float sc = 1.0f / 4096.0f;
    float2* dst = (float2*)yT + (size_t)bc * 2048;
#pragma unroll
    for (int k1 = 0; k1 < 8; ++k1) {                // keep first 2048 cplx (=4096 reals)
        int idx = t + (k1 << 8);
        dst[idx] = make_float2(vr[k1] * sc, vi[k1] * sc);
    }
}

// ---------------------------------------------------------------- launch
extern "C" void kernel_launch(void* const* d_in, const int* in_sizes, int n_in,
                              void* d_out, int out_size, void* d_ws, size_t ws_size,
                              hipStream_t stream) {
    const float* x     = (const float*)d_in[0];
    const float* pp_w  = (const float*)d_in[1];
    const float* pp_b  = (const float*)d_in[2];
    const float* ln_w  = (const float*)d_in[3];
    const float* ln_b  = (const float*)d_in[4];
    const float* lw    = (const float*)d_in[5];
    const float* lb    = (const float*)d_in[6];
    const float* oln_w = (const float*)d_in[7];
    const float* oln_b = (const float*)d_in[8];
    const float* out_w = (const float*)d_in[9];
    const float* out_b = (const float*)d_in[10];
    float* out = (float*)d_out;
    char* ws = (char*)d_ws;

    // ws layout (bytes), total ~67.2 MB:
    //   tw  @ 0       : 4096 float2                (32 KB)
    //   xT  @ 64K     : 2048x4096 f32  (33.55 MB)  x channel-major; aliased by yT
    //   aU  @ +33.5M  : 4096x512  f32  ( 8.39 MB)  rpe out, m-major
    //   aT  @ +8.39M  : 512x4096  f32  ( 8.39 MB)  rpe out, channel-major
    //   Za  @ +8.39M  : 512x4096  cplx (16.78 MB)  packed spectra of a
    float2* tw = (float2*)(ws);
    float*  xT = (float*)(ws + 65536u);
    float*  aU = (float*)(ws + 65536u + 33554432u);
    float*  aT = (float*)(ws + 65536u + 33554432u + 8388608u);
    float2* Za = (float2*)(ws + 65536u + 33554432u + 16777216u);
    float*  yT = xT;   // xT dead after the fused kernel consumes it

    k_twiddle<<<16, 256, 0, stream>>>(tw);
    // x [32 slabs][4096 n][64 d] -> xT [32][64 d][4096 n]
    k_transpose<<<dim3(1, 64, 32), 256, 0, stream>>>(x, xT, 4096, 64);
    k_rpe<<<512, 256, 0, stream>>>(pp_w, pp_b, ln_w, ln_b, lw, lb,
                                   oln_w, oln_b, out_w, out_b, aU);
    // aU [4096 m][512 c] -> aT [512 c][4096 m]
    k_transpose<<<dim3(8, 64, 1), 256, 0, stream>>>(aU, aT, 4096, 512);
    k_fft_fwd<<<CHA, 256, 0, stream>>>((const float2*)aT, Za, tw);
    k_fft_conv_inv<<<CHX, 256, 0, stream>>>((const float2*)xT, Za, tw, yT);
    // yT [32][64 d][4096 n] -> out [32][4096 n][64 d]
    k_transpose<<<dim3(64, 1, 32), 256, 0, stream>>>(yT, out, 64, 4096);
}